// Round 10
// baseline (539.035 us; speedup 1.0000x reference)
//
#include <hip/hip_runtime.h>
#include <hip/hip_bf16.h>
#include <math.h>

#define N_BATCH 8
#define WDIM 64
#define TDIM 8192
#define KBINS 2048
#define NROWS (N_BATCH * TDIM)          // 65536
#define XSIZE (N_BATCH * WDIM * TDIM)   // 4194304
#define XL_OFF 0
#define XD_OFF NROWS
#define SCAL_OFF (NROWS + XSIZE)

#define MT 64                           // rows per block
#define XST 72                          // bf16 LDS x row stride
#define TAU 0.05f
#define MAXFLAG 8192
#define NBLK (NROWS / MT)               // 1024
#define RB 64                           // recheck rows per batch

// ws layout (bytes):
//   0       : float k2[KBINS]            (8192)
//   8192    : int   flag_cnt
//   8256    : int   flags[MAXFLAG]       (32768)
//   41024   : u64   slots[MAXFLAG]       (65536)
//   106560  : float part[4][NBLK]        (16384)
//   122944  : char  kfrag[128*4096]      (524288)
//   647296  : float kT[64][2048]         (524288, optional)
//   1171584 : float xf[MAXFLAG][64]      (2097152, optional -> coalesced recheck)
#define WS_K2_OFF   0
#define WS_CNT_OFF  8192
#define WS_FLAG_OFF 8256
#define WS_SLOT_OFF 41024
#define WS_PART_OFF 106560
#define WS_KF_OFF   122944
#define WS_KT_OFF   647296
#define WS_KT_END   (WS_KT_OFF + (size_t)WDIM * KBINS * 4)
#define WS_XF_OFF   WS_KT_END
#define WS_XF_END   (WS_XF_OFF + (size_t)MAXFLAG * WDIM * 4)

typedef __attribute__((ext_vector_type(8))) short bf16x8;
typedef __attribute__((ext_vector_type(4))) float f32x4;
typedef unsigned long long u64;

static __device__ __forceinline__ short f2bf(float v) {
  __hip_bfloat16 b = __float2bfloat16(v);
  return *reinterpret_cast<short*>(&b);
}
static __device__ __forceinline__ float bf2f(short s) {
  unsigned int u = ((unsigned int)(unsigned short)s) << 16;
  return __uint_as_float(u);
}

#define GLOAD_LDS(gsrc, ldst)                                            \
  __builtin_amdgcn_global_load_lds(                                      \
      (const __attribute__((address_space(1))) unsigned int*)(gsrc),     \
      (__attribute__((address_space(3))) unsigned int*)(ldst), 16, 0, 0)

// s_waitcnt immediates (gfx9): vmcnt[3:0] | expcnt<<4 | lgkmcnt<<8
#define WAIT_VM4 0x0F74
#define WAIT_VM0 0x0F70
#define SBAR() asm volatile("s_barrier" ::: "memory")

// prep: 1 block per 16-code tile. np-bit-exact k2 + fragment-ordered split-bf16
// codebook + optional kT transpose + ws init.
__global__ void prep_kernel(const float* __restrict__ kg, float* __restrict__ k2,
                            char* __restrict__ kfrag, float* __restrict__ kT,
                            int* __restrict__ cnt, u64* __restrict__ slots) {
  __shared__ float skc[16 * 65];
  const int tid  = threadIdx.x;
  const int tile = blockIdx.x;           // 0..127
  const int c0   = tile * 16;
  if (tile == 0 && tid == 0) *cnt = 0;
  if (tid < 64) slots[tile * 64 + tid] = ~0ULL;
  {
    const float4* g4 = (const float4*)(kg + (size_t)c0 * WDIM);
    int code = tid >> 4, w = (tid & 15) * 4;
    *(float4*)&skc[code * 65 + w] = g4[tid];
  }
  __syncthreads();
  if (tid < 16) {   // np-bit-exact k2 (8-accumulator pairwise)
    const float* kr = &skc[tid * 65];
    float r[8];
#pragma unroll
    for (int l = 0; l < 8; ++l) r[l] = __fmul_rn(kr[l], kr[l]);
    for (int i = 8; i < WDIM; i += 8) {
#pragma unroll
      for (int l = 0; l < 8; ++l)
        r[l] = __fadd_rn(r[l], __fmul_rn(kr[i + l], kr[i + l]));
    }
    k2[c0 + tid] = __fadd_rn(__fadd_rn(__fadd_rn(r[0], r[1]), __fadd_rn(r[2], r[3])),
                             __fadd_rn(__fadd_rn(r[4], r[5]), __fadd_rn(r[6], r[7])));
  }
  if (kT) {   // transposed copy for coalesced recheck reads (bit-exact values)
    const int code = tid & 15;
#pragma unroll
    for (int j = 0; j < 4; ++j) {
      int w = (tid >> 4) + 16 * j;
      kT[(size_t)w * KBINS + c0 + code] = skc[code * 65 + w];
    }
  }
  {
    const int sub  = tid >> 6;           // 0..3
    const int lane = tid & 63;
    const int lcol = lane & 15;
    const int quad = lane >> 4;
    const float* src = &skc[lcol * 65 + (sub & 1) * 32 + quad * 8];
    const bool lo = (sub >= 2);
    short tmp[8];
#pragma unroll
    for (int i = 0; i < 8; ++i) {
      float v = src[i];
      short h = f2bf(v);
      tmp[i] = lo ? f2bf(v - bf2f(h)) : h;
    }
    char* dst = kfrag + (size_t)tile * 4096 + sub * 1024 + lane * 16;
    *(bf16x8*)dst = *(const bf16x8*)tmp;
  }
}

// main: R2-PROVEN split-bf16 MFMA scan. 256 thr = 4 waves x 16 rows; shared
// 3-slot ring filled by wave0; one raw s_barrier per 16-code step.
// xf export is FUSED into the commit loop via an LDS rowSlot map (values are
// already in registers there -> zero extra global loads).
__launch_bounds__(256, 4)
__global__ void vq_mono(const float* __restrict__ x,
                        const float* __restrict__ kg,
                        const float* __restrict__ k2g,
                        const char* __restrict__ kfrag,
                        float* __restrict__ out,
                        float* __restrict__ part,
                        int* __restrict__ flag_cnt,
                        int* __restrict__ flags,
                        float* __restrict__ xf) {
  __shared__ __align__(16) char smem[20480];
  char*  kbuf = smem;
  float* k2f  = (float*)(smem + 12288);
  short* sxh = (short*)smem;
  short* sxl = (short*)(smem + 9216);
  float* kd  = (float*)smem;
  int*   sIdx      = (int*)  (smem + 18432);
  float* sPair     = (float*)(smem + 18688);
  int*   sFlagCnt  = (int*)  (smem + 18752);
  int*   sFlagBase = (int*)  (smem + 18756);
  int*   sFlagList = (int*)  (smem + 18760);   // 64 ints, ends 19016
  int*   rowSlot   = (int*)  (smem + 19016);   // 64 ints, ends 19272

  const int tid  = threadIdx.x;
  const int blk  = blockIdx.x;
  const int row0 = blk * MT;
  const int n    = row0 >> 13;
  const int t0   = row0 & (TDIM - 1);

  const int r  = tid & 63;
  const int wh = tid >> 6;
  float x2p = 0.f, sxp = 0.f;
  const float* xb = x + (size_t)n * WDIM * TDIM + t0 + r;
#pragma unroll 8
  for (int i = 0; i < 16; ++i) {
    int w = 4 * i + wh;
    float v = xb[(size_t)w * TDIM];
    x2p = fmaf(v, v, x2p);
    sxp += v;
    short h = f2bf(v);
    sxh[r * XST + w] = h;
    sxl[r * XST + w] = f2bf(v - bf2f(h));
  }
  __syncthreads();

  const int wave = tid >> 6;
  const int lane = tid & 63;
  const int lcol = lane & 15;
  const int quad = lane >> 4;
  const int rA = wave * 16 + lcol;
  bf16x8 ah0 = *(const bf16x8*)&sxh[rA * XST + 0  + quad * 8];
  bf16x8 ah1 = *(const bf16x8*)&sxh[rA * XST + 32 + quad * 8];
  bf16x8 al0 = *(const bf16x8*)&sxl[rA * XST + 0  + quad * 8];
  bf16x8 al1 = *(const bf16x8*)&sxl[rA * XST + 32 + quad * 8];
  __syncthreads();

  float bd[4], b2[4];
  int   bi[4];
#pragma unroll
  for (int i = 0; i < 4; ++i) { bd[i] = 3.0e38f; b2[i] = 3.0e38f; bi[i] = 0; }

  const char* kfg = kfrag;

#define VQM_ISSUE(C, B)                                                      \
  if ((C) < 128) {                                                           \
    const char* s = kfg + (size_t)(C) * 4096 + (lane << 4);                  \
    char* d = kbuf + (B) * 4096;                                             \
    GLOAD_LDS(s, d);                                                         \
    GLOAD_LDS(s + 1024, d + 1024);                                           \
    GLOAD_LDS(s + 2048, d + 2048);                                           \
    GLOAD_LDS(s + 3072, d + 3072);                                           \
  }

  {
    const float4* k24 = (const float4*)k2g;
    *(float4*)&k2f[tid * 8]     = k24[tid * 2];
    *(float4*)&k2f[tid * 8 + 4] = k24[tid * 2 + 1];
  }
  if (wave == 0) {
    VQM_ISSUE(0, 0)
    VQM_ISSUE(1, 1)
  }
  asm volatile("s_waitcnt lgkmcnt(0)\n\ts_barrier" ::: "memory");

#define VQM_STEP(C, RB_, PB, WAITIMM)                                        \
  {                                                                          \
    if (wave == 0) __builtin_amdgcn_s_waitcnt(WAITIMM);                      \
    SBAR();                                                                  \
    const char* tb = kbuf + (RB_) * 4096;                                    \
    bf16x8 bh0 = *(const bf16x8*)(tb + 0    + (lane << 4));                  \
    bf16x8 bh1 = *(const bf16x8*)(tb + 1024 + (lane << 4));                  \
    bf16x8 bl0 = *(const bf16x8*)(tb + 2048 + (lane << 4));                  \
    bf16x8 bl1 = *(const bf16x8*)(tb + 3072 + (lane << 4));                  \
    float k2c = k2f[(C) * 16 + lcol];                                        \
    if (wave == 0) { VQM_ISSUE((C) + 2, PB) }                                \
    f32x4 p = {0.f, 0.f, 0.f, 0.f};                                          \
    p = __builtin_amdgcn_mfma_f32_16x16x32_bf16(ah0, bh0, p, 0, 0, 0);       \
    p = __builtin_amdgcn_mfma_f32_16x16x32_bf16(ah1, bh1, p, 0, 0, 0);       \
    p = __builtin_amdgcn_mfma_f32_16x16x32_bf16(ah0, bl0, p, 0, 0, 0);       \
    p = __builtin_amdgcn_mfma_f32_16x16x32_bf16(ah1, bl1, p, 0, 0, 0);       \
    p = __builtin_amdgcn_mfma_f32_16x16x32_bf16(al0, bh0, p, 0, 0, 0);       \
    p = __builtin_amdgcn_mfma_f32_16x16x32_bf16(al1, bh1, p, 0, 0, 0);       \
    const int code = (C) * 16 + lcol;                                        \
    _Pragma("unroll")                                                        \
    for (int i = 0; i < 4; ++i) {                                            \
      float d0 = fmaf(-2.f, p[i], k2c);                                      \
      float nb2 = __builtin_amdgcn_fmed3f(bd[i], d0, b2[i]);                 \
      bool lt0 = d0 < bd[i];                                                 \
      bd[i] = lt0 ? d0 : bd[i];                                              \
      bi[i] = lt0 ? code : bi[i];                                            \
      b2[i] = nb2;                                                           \
    }                                                                        \
  }

  for (int c = 0; c < 126; c += 3) {
    VQM_STEP(c,     0, 2, WAIT_VM4)
    VQM_STEP(c + 1, 1, 0, WAIT_VM4)
    VQM_STEP(c + 2, 2, 1, WAIT_VM4)
  }
  VQM_STEP(126, 0, 2, WAIT_VM4)
  VQM_STEP(127, 1, 0, WAIT_VM0)
#undef VQM_STEP
#undef VQM_ISSUE

#pragma unroll
  for (int m = 1; m < 16; m <<= 1) {
#pragma unroll
    for (int i = 0; i < 4; ++i) {
      float od  = __shfl_xor(bd[i], m, 64);
      float od2 = __shfl_xor(b2[i], m, 64);
      int   oi  = __shfl_xor(bi[i], m, 64);
      float nb2 = fminf(fminf(b2[i], od2), fmaxf(bd[i], od));
      bool take = (od < bd[i]) || (od == bd[i] && oi < bi[i]);
      bd[i] = take ? od : bd[i];
      bi[i] = take ? oi : bi[i];
      b2[i] = nb2;
    }
  }

  __syncthreads();
  if (tid == 0) *sFlagCnt = 0;
  if (tid < MT) rowSlot[tid] = -1;
  __syncthreads();

  float fit_p = 0.f;
  if (lcol == 0) {
#pragma unroll
    for (int i = 0; i < 4; ++i) {
      int rloc = wave * 16 + quad * 4 + i;
      int rowg = row0 + rloc;
      out[XL_OFF + rowg] = (float)bi[i];
      sIdx[rloc] = bi[i];
      fit_p += bd[i];
      if (b2[i] - bd[i] < TAU) {
        int slot = atomicAdd(sFlagCnt, 1);
        sFlagList[slot] = rowg;
      }
    }
  }
  __syncthreads();

  int nloc = *sFlagCnt;
  if (tid == 0 && nloc > 0) *sFlagBase = atomicAdd(flag_cnt, nloc);
  __syncthreads();
  if (tid < nloc) {
    int gs = *sFlagBase + tid;
    if (gs < MAXFLAG) {
      flags[gs] = sFlagList[tid];
      rowSlot[sFlagList[tid] - row0] = gs;
    }
  }

  {
    int rr = tid >> 2, q4 = tid & 3;
    const float4* kr4 = (const float4*)(kg + (size_t)sIdx[rr] * WDIM) + q4 * 4;
    float4* dst = (float4*)&kd[rr * 68 + q4 * 16];
#pragma unroll
    for (int j = 0; j < 4; ++j) dst[j] = kr4[j];
  }
  __syncthreads();

  // commit loop with fused xf export (predicated stores, values in regs)
  float commit_p = 0.f;
  const int sl = xf ? rowSlot[r] : -1;
  float* xdb = out + XD_OFF + (size_t)n * WDIM * TDIM + t0 + r;
#pragma unroll 8
  for (int i = 0; i < 16; ++i) {
    int w = 4 * i + wh;
    float xvv = xb[(size_t)w * TDIM];
    float kvv = kd[r * 68 + w];
    float df = kvv - xvv;
    commit_p = fmaf(df, df, commit_p);
    xdb[(size_t)w * TDIM] = kvv;
    if (sl >= 0) xf[(size_t)sl * WDIM + w] = xvv;
  }

  float v0 = sxp, v1 = x2p, v2 = commit_p, v3 = fit_p;
#pragma unroll
  for (int off = 32; off > 0; off >>= 1) {
    v0 += __shfl_down(v0, off, 64);
    v1 += __shfl_down(v1, off, 64);
    v2 += __shfl_down(v2, off, 64);
    v3 += __shfl_down(v3, off, 64);
  }
  if (lane == 0) {
    sPair[wave * 4 + 0] = v0;
    sPair[wave * 4 + 1] = v1;
    sPair[wave * 4 + 2] = v2;
    sPair[wave * 4 + 3] = v3;
  }
  __syncthreads();
  if (tid == 0) {
    float x2sum = sPair[1] + sPair[5] + sPair[9] + sPair[13];
    part[0 * NBLK + blk] = sPair[0] + sPair[4] + sPair[8] + sPair[12];
    part[1 * NBLK + blk] = x2sum;
    part[2 * NBLK + blk] = sPair[2] + sPair[6] + sPair[10] + sPair[14];
    part[3 * NBLK + blk] = (sPair[3] + sPair[7] + sPair[11] + sPair[15]) + x2sum;
  }
}

// recheck pass 1 (GEMM-tiled): block = (64-row batch, 256-code chunk).
// grid = 128 x 8 = 1024 blocks. Rows staged TRANSPOSED in LDS (xrT[w][rr],
// coalesced from xf); thread caches its code in kreg[64] (coalesced via kT).
// Per 8-row group: 8 independent fmaf chains fed by two broadcast float4 LDS
// reads per w. kT traffic: 64 KB/block = 64 MB total (/64 vs per-row sweeps).
// Argmin: fminf butterfly + ballot (lowest lane = lowest code -> exact
// tie-break), u64 cross-wave + global atomicMin merge. Per-(row,code) fmaf
// w-order, sx2-2c+k2 combination, and pairwise x2 chains are byte-identical
// to the proven bit-exact form.
__launch_bounds__(256, 2)
__global__ void recheck_scan(const float* __restrict__ x,
                             const float* __restrict__ xf,
                             const float* __restrict__ kg,
                             const float* __restrict__ kT,
                             const float* __restrict__ k2g,
                             const int* __restrict__ flag_cnt,
                             const int* __restrict__ flags,
                             u64* __restrict__ slots) {
  __shared__ __align__(16) float xrT[WDIM * 72];   // [w][rr], 18432 B
  __shared__ float sx2r[RB];
  __shared__ u64   wkey[RB][4];
  __shared__ int   rowsA[RB];
  const int tid  = threadIdx.x;
  const int lane = tid & 63;
  const int wv   = tid >> 6;
  int nf = *flag_cnt;
  if (nf > MAXFLAG) nf = MAXFLAG;
  const int batch = blockIdx.x >> 3;
  const int chunk = blockIdx.x & 7;
  const int f0 = batch * RB;
  if (f0 >= nf) return;
  const int nr = min(RB, nf - f0);

  // ---- stage rows transposed into LDS ----
  if (xf) {
    const float* src = xf + (size_t)f0 * WDIM;
#pragma unroll
    for (int i = 0; i < 16; ++i) {
      int idx = tid + i * 256;           // contiguous in xf -> coalesced
      int rr = idx >> 6, w = idx & 63;
      float v = (rr < nr) ? src[idx] : 0.f;
      xrT[w * 72 + rr] = v;
    }
  } else {
    if (tid < RB) rowsA[tid] = (tid < nr) ? flags[f0 + tid] : 0;
    __syncthreads();
#pragma unroll
    for (int i = 0; i < 16; ++i) {
      int idx = tid + i * 256;
      int rr = idx >> 6, w = idx & 63;
      float v = 0.f;
      if (rr < nr) {
        int row = rowsA[rr];
        int n = row >> 13, t = row & (TDIM - 1);
        v = x[(size_t)n * WDIM * TDIM + (size_t)w * TDIM + t];
      }
      xrT[w * 72 + rr] = v;
    }
  }
  __syncthreads();

  // ---- per-row np-pairwise x2 (bit-exact chain) ----
  if (tid < RB) {
    float r8[8];
#pragma unroll
    for (int l = 0; l < 8; ++l) {
      float vv = xrT[l * 72 + tid];
      r8[l] = __fmul_rn(vv, vv);
    }
    for (int i = 8; i < WDIM; i += 8) {
#pragma unroll
      for (int l = 0; l < 8; ++l) {
        float vv = xrT[(i + l) * 72 + tid];
        r8[l] = __fadd_rn(r8[l], __fmul_rn(vv, vv));
      }
    }
    sx2r[tid] = __fadd_rn(__fadd_rn(__fadd_rn(r8[0], r8[1]), __fadd_rn(r8[2], r8[3])),
                          __fadd_rn(__fadd_rn(r8[4], r8[5]), __fadd_rn(r8[6], r8[7])));
  }
  __syncthreads();

  // ---- this thread's code -> registers (coalesced via kT) ----
  const int j = chunk * 256 + tid;
  float kreg[WDIM];
  if (kT) {
#pragma unroll
    for (int w = 0; w < WDIM; ++w) kreg[w] = kT[(size_t)w * KBINS + j];
  } else {
    const float* kr = kg + (size_t)j * WDIM;
#pragma unroll
    for (int w = 0; w < WDIM; ++w) kreg[w] = kr[w];
  }
  const float k2j = k2g[j];

  // ---- 8 row-groups x 8 independent chains ----
#pragma unroll 1
  for (int rg = 0; rg < 8; ++rg) {
    float acc[8];
#pragma unroll
    for (int t8 = 0; t8 < 8; ++t8) acc[t8] = 0.f;
#pragma unroll
    for (int w = 0; w < WDIM; ++w) {
      float4 xa = *(const float4*)&xrT[w * 72 + rg * 8];
      float4 xb4 = *(const float4*)&xrT[w * 72 + rg * 8 + 4];
      acc[0] = __fmaf_rn(xa.x, kreg[w], acc[0]);
      acc[1] = __fmaf_rn(xa.y, kreg[w], acc[1]);
      acc[2] = __fmaf_rn(xa.z, kreg[w], acc[2]);
      acc[3] = __fmaf_rn(xa.w, kreg[w], acc[3]);
      acc[4] = __fmaf_rn(xb4.x, kreg[w], acc[4]);
      acc[5] = __fmaf_rn(xb4.y, kreg[w], acc[5]);
      acc[6] = __fmaf_rn(xb4.z, kreg[w], acc[6]);
      acc[7] = __fmaf_rn(xb4.w, kreg[w], acc[7]);
    }
#pragma unroll
    for (int t8 = 0; t8 < 8; ++t8) {
      const int rr = rg * 8 + t8;
      float d = __fadd_rn(__fsub_rn(sx2r[rr], __fmul_rn(2.0f, acc[t8])), k2j);
      float dmin = d;
#pragma unroll
      for (int m = 1; m < 64; m <<= 1)
        dmin = fminf(dmin, __shfl_xor(dmin, m, 64));
      u64 mask = __ballot(d == dmin);
      int lowlane = __ffsll(mask) - 1;
      u64 key = ((u64)__float_as_uint(dmin) << 32)
              | (unsigned)(chunk * 256 + wv * 64 + lowlane);
      if (lane == 0) wkey[rr][wv] = key;
    }
  }
  __syncthreads();
  if (tid < nr) {
    u64 b = wkey[tid][0];
#pragma unroll
    for (int k = 1; k < 4; ++k) b = (wkey[tid][k] < b) ? wkey[tid][k] : b;
    atomicMin(&slots[f0 + tid], b);
  }
}

// recheck pass 2: persistent write-back.
__global__ void recheck_write(const float* __restrict__ kg,
                              const int* __restrict__ flag_cnt,
                              const int* __restrict__ flags,
                              const u64* __restrict__ slots,
                              float* __restrict__ out) {
  int nf = *flag_cnt;
  if (nf > MAXFLAG) nf = MAXFLAG;
  const int w = threadIdx.x;
  for (int fi = blockIdx.x; fi < nf; fi += 256) {
    const int row = flags[fi];
    const int n = row >> 13;
    const int t = row & (TDIM - 1);
    const int j = (int)(slots[fi] & 0xFFFFFFFFULL);
    if (w == 0) out[XL_OFF + row] = (float)j;
    out[XD_OFF + (size_t)n * WDIM * TDIM + (size_t)w * TDIM + t] = kg[(size_t)j * WDIM + w];
  }
}

// finalize: sum per-block partials (fp64) + emit the 3 scalars.
__global__ void finalize_kernel(const float* __restrict__ part, float* __restrict__ out) {
  __shared__ double sred[4][64];
  const int tid = threadIdx.x;     // 256
  const int lane = tid & 63;
  const int wv = tid >> 6;
  double a[4] = {0.0, 0.0, 0.0, 0.0};
  for (int i = tid; i < NBLK; i += 256) {
#pragma unroll
    for (int q = 0; q < 4; ++q) a[q] += (double)part[q * NBLK + i];
  }
#pragma unroll
  for (int off = 32; off > 0; off >>= 1) {
#pragma unroll
    for (int q = 0; q < 4; ++q)
      a[q] += __shfl_down(a[q], off, 64);
  }
  if (lane == 0) {
#pragma unroll
    for (int q = 0; q < 4; ++q) sred[q][wv] = a[q];
  }
  __syncthreads();
  if (tid == 0) {
    double s0 = 0, s1 = 0, s2 = 0, s3 = 0;
#pragma unroll
    for (int wv2 = 0; wv2 < 4; ++wv2) {
      s0 += sred[0][wv2]; s1 += sred[1][wv2];
      s2 += sred[2][wv2]; s3 += sred[3][wv2];
    }
    double size = (double)XSIZE;
    double commit = s2 / size;
    double fit = s3 / (double)NROWS;
    double mean = s0 / size;
    double var = s1 / size - mean * mean;
    if (var < 0.0) var = 0.0;
    out[SCAL_OFF + 0] = (float)commit;
    out[SCAL_OFF + 1] = (float)fit;
    out[SCAL_OFF + 2] = (float)sqrt(var);
  }
}

extern "C" void kernel_launch(void* const* d_in, const int* in_sizes, int n_in,
                              void* d_out, int out_size, void* d_ws, size_t ws_size,
                              hipStream_t stream) {
  const float* x = (const float*)d_in[0];
  const float* kg = (const float*)d_in[1];
  float* out = (float*)d_out;
  float* k2   = (float*)((char*)d_ws + WS_K2_OFF);
  int* cnt    = (int*)((char*)d_ws + WS_CNT_OFF);
  int* flags  = (int*)((char*)d_ws + WS_FLAG_OFF);
  u64* slots  = (u64*)((char*)d_ws + WS_SLOT_OFF);
  float* part = (float*)((char*)d_ws + WS_PART_OFF);
  char* kfrag = (char*)d_ws + WS_KF_OFF;
  float* kT   = (ws_size >= WS_KT_END) ? (float*)((char*)d_ws + WS_KT_OFF) : nullptr;
  float* xf   = (ws_size >= WS_XF_END) ? (float*)((char*)d_ws + WS_XF_OFF) : nullptr;

  hipLaunchKernelGGL(prep_kernel, dim3(KBINS / 16), dim3(256), 0, stream,
                     kg, k2, kfrag, kT, cnt, slots);
  hipLaunchKernelGGL(vq_mono, dim3(NBLK), dim3(256), 0, stream,
                     x, kg, k2, kfrag, out, part, cnt, flags, xf);
  hipLaunchKernelGGL(recheck_scan, dim3((MAXFLAG / RB) * 8), dim3(256), 0, stream,
                     x, xf, kg, kT, k2, cnt, flags, slots);
  hipLaunchKernelGGL(recheck_write, dim3(256), dim3(WDIM), 0, stream,
                     kg, cnt, flags, slots, out);
  hipLaunchKernelGGL(finalize_kernel, dim3(1), dim3(256), 0, stream, part, out);
}